// Round 8
// baseline (79.439 us; speedup 1.0000x reference)
//
#include <hip/hip_runtime.h>
#include <math.h>

// TDVP_V2: BATCH=16384 chains, N=64 sites, D=4, DIN=DOUT=2.
// v22: 2 blocks/CU phase-overlap attack.
// LEDGER (JSON): v15/17/18 = 77.70 | v20 (M-cache, norm-free interleaved
// scans, b128 row-quads) = 75.75 | v21b (NT x/y + unrolled scan) = 75.91
// (flat => L2-flush-tail theory dead). Calibration (v19 REP=5): harness
// floor 49.1 us (42 poison-fill + 7 small nodes), kernel ~26.7 us =
// F ~16.6 (non-repeated: ramp, x-read, y-store, prologue) + steady ~10.
// Remaining F theory: ONE 1024-thr block per CU => every barrier/memory
// phase stalls the whole CU; nothing overlaps across phases.
// v22: 512 blocks x 512 thr (32 chains x 16 segments), 56 KB LDS, VGPR<=128
// (launch_bounds(512,4)) => 2 independent blocks/CU: one block's
// x-read/ramp/y-store hides under the other's compute. Direct global x
// loads + y stores (32B/thread contiguous, sector-dense via half-wave
// pairing) delete x/y LDS staging and 2 of 4 barriers. Segments are
// half-wave: scans lane-masked (v15-proven ~free), A/B via LDS broadcast
// (v15-proven neutral vs s_load).
// Predicted: kernel 26.7 -> ~20-23 => JSON ~69-72; LDS_Block_Size 57344;
// absmax ~0.0039. If flat: F = ramp/cold-read floor => ROOFLINE call next.

#define RSQ(x) __builtin_amdgcn_rsqf((x) + 1e-30f)

__global__ __launch_bounds__(512, 4)
void tdvp_kernel(const float* __restrict__ x,
                 const float* __restrict__ A,
                 const float* __restrict__ Bw,
                 const float* __restrict__ scale,
                 float* __restrict__ y)
{
    __shared__ float sA[2048];   // A: 64 sites x 32 floats (8 KB)
    __shared__ float sB[4096];   // B: 64 sites x 64 floats (16 KB)
    __shared__ float sP[8192];   // [16 t][4 q][32 bb][4]   (32 KB)

    const int tid = threadIdx.x;
    const int bb  = tid & 31;    // chain in block
    const int s   = tid >> 5;    // segment 0..15 (half-wave granularity)

    // ---- stage A/B into LDS (coalesced float4: 1+2 per thread) -----------
    ((float4*)sA)[tid]       = ((const float4*)A)[tid];
    ((float4*)sB)[tid]       = ((const float4*)Bw)[tid];
    ((float4*)sB)[512 + tid] = ((const float4*)Bw)[512 + tid];

    // ---- direct x loads (32B/thread, contiguous, 32B-aligned) ------------
    const int n0 = s * 4;
    const float* xp = x + (size_t)blockIdx.x * 4096 + bb * 128 + n0 * 2;
    const float4 xv0 = *(const float4*)xp;
    const float4 xv1 = *(const float4*)(xp + 4);
    float xa[4], xc[4];
    {
        float r;
        r = RSQ(xv0.x*xv0.x + xv0.y*xv0.y); xa[0]=xv0.x*r; xc[0]=xv0.y*r;
        r = RSQ(xv0.z*xv0.z + xv0.w*xv0.w); xa[1]=xv0.z*r; xc[1]=xv0.w*r;
        r = RSQ(xv1.x*xv1.x + xv1.y*xv1.y); xa[2]=xv1.x*r; xc[2]=xv1.y*r;
        r = RSQ(xv1.z*xv1.z + xv1.w*xv1.w); xa[3]=xv1.z*r; xc[3]=xv1.w*r;
    }

    __syncthreads();   // barrier #1: A/B staged

    // ---- M cache from sA (broadcast ds_reads, 2-way = free) --------------
    float M[4][16];
    #pragma unroll
    for (int k = 0; k < 4; ++k) {
        const float4* Aq = (const float4*)&sA[(n0 + k) * 32];
        #pragma unroll
        for (int t = 0; t < 8; ++t) {
            const float4 q = Aq[t];
            M[k][2*t]   = fmaf(xc[k], q.y, xa[k] * q.x);
            M[k][2*t+1] = fmaf(xc[k], q.w, xa[k] * q.z);
        }
    }

    // ---- phase 1: P = M0*M1*M2*M3, Frobenius-normalized -> sP ------------
    {
        float P[16];
        #pragma unroll
        for (int e = 0; e < 16; ++e) P[e] = M[0][e];
        #pragma unroll
        for (int k = 1; k < 4; ++k) {
            float Pn[16];
            #pragma unroll
            for (int i = 0; i < 4; ++i) {
                #pragma unroll
                for (int j = 0; j < 4; ++j) {
                    float acc = P[i*4] * M[k][j];
                    acc = fmaf(P[i*4+1], M[k][4+j],  acc);
                    acc = fmaf(P[i*4+2], M[k][8+j],  acc);
                    acc = fmaf(P[i*4+3], M[k][12+j], acc);
                    Pn[i*4+j] = acc;
                }
            }
            #pragma unroll
            for (int e = 0; e < 16; ++e) P[e] = Pn[e];
        }
        float ss = 0.f;
        #pragma unroll
        for (int e = 0; e < 16; ++e) ss = fmaf(P[e], P[e], ss);
        const float rn = RSQ(ss);
        #pragma unroll
        for (int q = 0; q < 4; ++q)
            *(float4*)&sP[s * 512 + q * 128 + bb * 4] =
                make_float4(P[4*q]*rn, P[4*q+1]*rn, P[4*q+2]*rn, P[4*q+3]*rn);
    }
    __syncthreads();   // barrier #2: sP complete

    // ---- phase 2: interleaved prefix/suffix scans, norm-free, masked -----
    float v0 = 1.f, v1 = 0.f, v2 = 0.f, v3 = 0.f;   // prefix: v <- v * P_t
    float u0 = 1.f, u1 = 0.f, u2 = 0.f, u3 = 0.f;   // suffix: u <- P_t * u
    const int nsuf = 15 - s;
    #pragma unroll
    for (int i = 0; i < 15; ++i) {
        if (i < s) {               // lane-masked (half-wave divergence)
            const float4* pp = (const float4*)&sP[i * 512 + bb * 4];
            const float4 r0 = pp[0], r1 = pp[32], r2 = pp[64], r3 = pp[96];
            const float w0 = v0*r0.x + v1*r1.x + v2*r2.x + v3*r3.x;
            const float w1 = v0*r0.y + v1*r1.y + v2*r2.y + v3*r3.y;
            const float w2 = v0*r0.z + v1*r1.z + v2*r2.z + v3*r3.z;
            const float w3 = v0*r0.w + v1*r1.w + v2*r2.w + v3*r3.w;
            v0 = w0; v1 = w1; v2 = w2; v3 = w3;
        }
        if (i < nsuf) {            // t = 15 - i
            const float4* pp = (const float4*)&sP[(15 - i) * 512 + bb * 4];
            const float4 r0 = pp[0], r1 = pp[32], r2 = pp[64], r3 = pp[96];
            const float w0 = r0.x*u0 + r0.y*u1 + r0.z*u2 + r0.w*u3;
            const float w1 = r1.x*u0 + r1.y*u1 + r1.z*u2 + r1.w*u3;
            const float w2 = r2.x*u0 + r2.y*u1 + r2.z*u2 + r2.w*u3;
            const float w3 = r3.x*u0 + r3.y*u1 + r3.z*u2 + r3.w*u3;
            u0 = w0; u1 = w1; u2 = w2; u3 = w3;
        }
    }

    // ---- phase 3a: forward walk, vl per site (cached M, raw) -------------
    float vlA[4], vlB[4], vlC[4], vlD[4];
    {
        float a0 = v0, a1 = v1, a2 = v2, a3 = v3;
        #pragma unroll
        for (int k = 0; k < 4; ++k) {
            vlA[k] = a0; vlB[k] = a1; vlC[k] = a2; vlD[k] = a3;
            if (k == 3) break;
            const float t0 = a0*M[k][0] + a1*M[k][4] + a2*M[k][8]  + a3*M[k][12];
            const float t1 = a0*M[k][1] + a1*M[k][5] + a2*M[k][9]  + a3*M[k][13];
            const float t2 = a0*M[k][2] + a1*M[k][6] + a2*M[k][10] + a3*M[k][14];
            const float t3 = a0*M[k][3] + a1*M[k][7] + a2*M[k][11] + a3*M[k][15];
            a0 = t0; a1 = t1; a2 = t2; a3 = t3;
        }
    }

    // ---- phase 3b: backward walk + fused epilogue (B from LDS) -----------
    const float sc = scale[0];
    float yr[8];
    #pragma unroll
    for (int kk = 3; kk >= 0; --kk) {
        const int n = n0 + kk;

        const float arn = RSQ(u0*u0 + u1*u1 + u2*u2 + u3*u3);
        float aa0 = u0*arn, aa1 = u1*arn, aa2 = u2*arn, aa3 = u3*arn;
        if (n == 63) { aa0 = 1.f; aa1 = aa2 = aa3 = 0.f; }

        const float wn = RSQ(vlA[kk]*vlA[kk] + vlB[kk]*vlB[kk] +
                             vlC[kk]*vlC[kk] + vlD[kk]*vlD[kk]);
        float vv0 = vlA[kk]*wn, vv1 = vlB[kk]*wn, vv2 = vlC[kk]*wn, vv3 = vlD[kk]*wn;
        if (n == 0) { vv0 = 1.f; vv1 = vv2 = vv3 = 0.f; }

        const float vv[4] = {vv0, vv1, vv2, vv3};
        const float aa[4] = {aa0, aa1, aa2, aa3};
        const float4* Bq = (const float4*)&sB[n * 64];
        float H00 = 0.f, H01 = 0.f, H10 = 0.f, H11 = 0.f;
        #pragma unroll
        for (int i = 0; i < 4; ++i) {
            const float4 b0 = Bq[i*4+0], b1 = Bq[i*4+1],
                         b2 = Bq[i*4+2], b3 = Bq[i*4+3];
            const float c0 = vv[i]*aa[0], c1 = vv[i]*aa[1],
                        c2 = vv[i]*aa[2], c3 = vv[i]*aa[3];
            H00 = fmaf(c0, b0.x, H00); H01 = fmaf(c0, b0.y, H01);
            H10 = fmaf(c0, b0.z, H10); H11 = fmaf(c0, b0.w, H11);
            H00 = fmaf(c1, b1.x, H00); H01 = fmaf(c1, b1.y, H01);
            H10 = fmaf(c1, b1.z, H10); H11 = fmaf(c1, b1.w, H11);
            H00 = fmaf(c2, b2.x, H00); H01 = fmaf(c2, b2.y, H01);
            H10 = fmaf(c2, b2.z, H10); H11 = fmaf(c2, b2.w, H11);
            H00 = fmaf(c3, b3.x, H00); H01 = fmaf(c3, b3.y, H01);
            H10 = fmaf(c3, b3.z, H10); H11 = fmaf(c3, b3.w, H11);
        }
        const float rh = sc * RSQ(H00*H00 + H01*H01 + H10*H10 + H11*H11);
        H00 *= rh; H01 *= rh; H10 *= rh; H11 *= rh;
        if (__builtin_isnan(H00)) H00 = 0.f;
        if (__builtin_isnan(H01)) H01 = 0.f;
        if (__builtin_isnan(H10)) H10 = 0.f;
        if (__builtin_isnan(H11)) H11 = 0.f;
        H00 = fmaxf(H00, 0.f); H01 = fmaxf(H01, 0.f);
        H10 = fmaxf(H10, 0.f); H11 = fmaxf(H11, 0.f);

        yr[2*kk]     = fmaf(H01, xc[kk], H00 * xa[kk]);
        yr[2*kk + 1] = fmaf(H11, xc[kk], H10 * xa[kk]);

        if (kk > 0) {   // u <- M[kk].u  (raw suffix for site n-1)
            const float t0 = M[kk][0]*u0  + M[kk][1]*u1  + M[kk][2]*u2  + M[kk][3]*u3;
            const float t1 = M[kk][4]*u0  + M[kk][5]*u1  + M[kk][6]*u2  + M[kk][7]*u3;
            const float t2 = M[kk][8]*u0  + M[kk][9]*u1  + M[kk][10]*u2 + M[kk][11]*u3;
            const float t3 = M[kk][12]*u0 + M[kk][13]*u1 + M[kk][14]*u2 + M[kk][15]*u3;
            u0 = t0; u1 = t1; u2 = t2; u3 = t3;
        }
    }

    // ---- direct y stores (32B/thread contiguous, 32B-aligned) ------------
    {
        float* yp = y + (size_t)blockIdx.x * 4096 + bb * 128 + n0 * 2;
        *(float4*)yp       = make_float4(yr[0], yr[1], yr[2], yr[3]);
        *(float4*)(yp + 4) = make_float4(yr[4], yr[5], yr[6], yr[7]);
    }
}

extern "C" void kernel_launch(void* const* d_in, const int* in_sizes, int n_in,
                              void* d_out, int out_size, void* d_ws, size_t ws_size,
                              hipStream_t stream) {
    const float* x     = (const float*)d_in[0];
    const float* A     = (const float*)d_in[1];
    const float* B     = (const float*)d_in[2];
    const float* scale = (const float*)d_in[3];
    float* yp = (float*)d_out;
    const int batch  = in_sizes[0] / 128;    // 16384
    const int blocks = batch / 32;           // 512 blocks x 512 threads -> 2/CU
    tdvp_kernel<<<blocks, 512, 0, stream>>>(x, A, B, scale, yp);
}

// Round 9
// 76.431 us; speedup vs baseline: 1.0394x; 1.0394x over previous
//
#include <hip/hip_runtime.h>
#include <math.h>

// TDVP_V2: BATCH=16384 chains, N=64 sites, D=4, DIN=DOUT=2.
// v23: v20 minus all structural overhead — direct global x/y, ONE barrier.
// LEDGER (JSON): v15/17/18 = 77.70 | v20 = 75.75 (BEST) | v21b NT = 75.91
// (flat, flush-tail theory dead) | v22 2-blk/CU + LDS A/B = 79.44 (regress:
// A/B LDS broadcasts ~ +6us LDS pipe at 16 waves/CU >> ~2us overlap gain;
// wave-uniform segments force 1024-thr/1-blk/CU, S=8 halves waves => v20
// shape is the occupancy/SGPR local optimum).
// Calibration (v19): harness floor 49.1, v20 kernel ~26.7 = F 16.6 + steady 10.
// v23 theory: F contains the x/y LDS staging round-trips + 4 of 5 barrier
// drains, all serial at 1 block/CU. Direct x loads (32B/thread contiguous)
// and direct y stores (2x float4 from regs) make sU = sP only => exactly one
// __syncthreads (after sP write, before scan reads). Everything else = v20:
// SGPR A/B, M[4][16] cache, norm-free interleaved scans, b128 row-quads.
// VGPR ~118 (<=128, 4 waves/SIMD kept).
// Predicted: kernel -1..-2.5 us => JSON 73.5-75.0; absmax 0.0039; LDS 65536.
// If flat: remaining F = dispatch + cold-mem floor => near-floor call.

#define RSQ(x) __builtin_amdgcn_rsqf((x) + 1e-30f)

__global__ __launch_bounds__(1024, 4)
void tdvp_kernel(const float* __restrict__ x,
                 const float* __restrict__ A,
                 const float* __restrict__ Bw,
                 const float* __restrict__ scale,
                 float* __restrict__ y)
{
    // sP only: [16 t][4 q][64 bb][4] = 64 KB
    __shared__ float sP[16384];

    const int tid = threadIdx.x;
    const int bb  = tid & 63;                                  // chain in block
    const int s   = __builtin_amdgcn_readfirstlane(tid >> 6);  // segment 0..15

    // ---- direct x loads: 32B/thread contiguous (sites n0..n0+3) ----------
    const int n0 = s * 4;
    const float* xp = x + (size_t)blockIdx.x * 8192 + bb * 128 + n0 * 2;
    const float4 xv0 = *(const float4*)xp;
    const float4 xv1 = *(const float4*)(xp + 4);
    float xa[4], xc[4];
    {
        float r;
        r = RSQ(xv0.x*xv0.x + xv0.y*xv0.y); xa[0]=xv0.x*r; xc[0]=xv0.y*r;
        r = RSQ(xv0.z*xv0.z + xv0.w*xv0.w); xa[1]=xv0.z*r; xc[1]=xv0.w*r;
        r = RSQ(xv1.x*xv1.x + xv1.y*xv1.y); xa[2]=xv1.x*r; xc[2]=xv1.y*r;
        r = RSQ(xv1.z*xv1.z + xv1.w*xv1.w); xa[3]=xv1.z*r; xc[3]=xv1.w*r;
    }

    // ---- M cache: wave-uniform A -> s_loads -----------------------------
    float M[4][16];
    #pragma unroll
    for (int k = 0; k < 4; ++k) {
        const float* Ak = A + (size_t)(n0 + k) * 32;
        #pragma unroll
        for (int e = 0; e < 16; ++e)
            M[k][e] = fmaf(xc[k], Ak[2*e+1], xa[k] * Ak[2*e]);
    }

    // ---- phase 1: P = M0*M1*M2*M3, Frobenius-normalized -> sP ------------
    {
        float P[16];
        #pragma unroll
        for (int e = 0; e < 16; ++e) P[e] = M[0][e];
        #pragma unroll
        for (int k = 1; k < 4; ++k) {
            float Pn[16];
            #pragma unroll
            for (int i = 0; i < 4; ++i) {
                #pragma unroll
                for (int j = 0; j < 4; ++j) {
                    float acc = P[i*4] * M[k][j];
                    acc = fmaf(P[i*4+1], M[k][4+j],  acc);
                    acc = fmaf(P[i*4+2], M[k][8+j],  acc);
                    acc = fmaf(P[i*4+3], M[k][12+j], acc);
                    Pn[i*4+j] = acc;
                }
            }
            #pragma unroll
            for (int e = 0; e < 16; ++e) P[e] = Pn[e];
        }
        float ss = 0.f;
        #pragma unroll
        for (int e = 0; e < 16; ++e) ss = fmaf(P[e], P[e], ss);
        const float rn = RSQ(ss);
        #pragma unroll
        for (int q = 0; q < 4; ++q)
            *(float4*)&sP[s * 1024 + q * 256 + bb * 4] =
                make_float4(P[4*q]*rn, P[4*q+1]*rn, P[4*q+2]*rn, P[4*q+3]*rn);
    }
    __syncthreads();   // the ONLY barrier: sP complete before scan reads

    // ---- phase 2: interleaved prefix/suffix scans, norm-free -------------
    float v0 = 1.f, v1 = 0.f, v2 = 0.f, v3 = 0.f;   // prefix: v <- v * P_t
    float u0 = 1.f, u1 = 0.f, u2 = 0.f, u3 = 0.f;   // suffix: u <- P_t * u
    const int nsuf = 15 - s;
    #pragma unroll
    for (int i = 0; i < 15; ++i) {
        if (i < s) {               // wave-uniform
            const float4* pp = (const float4*)&sP[i * 1024 + bb * 4];
            const float4 r0 = pp[0], r1 = pp[64], r2 = pp[128], r3 = pp[192];
            const float w0 = v0*r0.x + v1*r1.x + v2*r2.x + v3*r3.x;
            const float w1 = v0*r0.y + v1*r1.y + v2*r2.y + v3*r3.y;
            const float w2 = v0*r0.z + v1*r1.z + v2*r2.z + v3*r3.z;
            const float w3 = v0*r0.w + v1*r1.w + v2*r2.w + v3*r3.w;
            v0 = w0; v1 = w1; v2 = w2; v3 = w3;
        }
        if (i < nsuf) {            // wave-uniform, t = 15 - i
            const float4* pp = (const float4*)&sP[(15 - i) * 1024 + bb * 4];
            const float4 r0 = pp[0], r1 = pp[64], r2 = pp[128], r3 = pp[192];
            const float w0 = r0.x*u0 + r0.y*u1 + r0.z*u2 + r0.w*u3;
            const float w1 = r1.x*u0 + r1.y*u1 + r1.z*u2 + r1.w*u3;
            const float w2 = r2.x*u0 + r2.y*u1 + r2.z*u2 + r2.w*u3;
            const float w3 = r3.x*u0 + r3.y*u1 + r3.z*u2 + r3.w*u3;
            u0 = w0; u1 = w1; u2 = w2; u3 = w3;
        }
    }

    // ---- phase 3a: forward walk, vl per site (cached M, raw) -------------
    float vlA[4], vlB[4], vlC[4], vlD[4];
    {
        float a0 = v0, a1 = v1, a2 = v2, a3 = v3;
        #pragma unroll
        for (int k = 0; k < 4; ++k) {
            vlA[k] = a0; vlB[k] = a1; vlC[k] = a2; vlD[k] = a3;
            if (k == 3) break;
            const float t0 = a0*M[k][0] + a1*M[k][4] + a2*M[k][8]  + a3*M[k][12];
            const float t1 = a0*M[k][1] + a1*M[k][5] + a2*M[k][9]  + a3*M[k][13];
            const float t2 = a0*M[k][2] + a1*M[k][6] + a2*M[k][10] + a3*M[k][14];
            const float t3 = a0*M[k][3] + a1*M[k][7] + a2*M[k][11] + a3*M[k][15];
            a0 = t0; a1 = t1; a2 = t2; a3 = t3;
        }
    }

    // ---- phase 3b: backward walk + fused epilogue -> y registers ---------
    const float sc = scale[0];
    float yr[8];
    #pragma unroll
    for (int kk = 3; kk >= 0; --kk) {
        const int n = n0 + kk;

        const float arn = RSQ(u0*u0 + u1*u1 + u2*u2 + u3*u3);
        float aa0 = u0*arn, aa1 = u1*arn, aa2 = u2*arn, aa3 = u3*arn;
        if (n == 63) { aa0 = 1.f; aa1 = aa2 = aa3 = 0.f; }

        const float wn = RSQ(vlA[kk]*vlA[kk] + vlB[kk]*vlB[kk] +
                             vlC[kk]*vlC[kk] + vlD[kk]*vlD[kk]);
        float vv0 = vlA[kk]*wn, vv1 = vlB[kk]*wn, vv2 = vlC[kk]*wn, vv3 = vlD[kk]*wn;
        if (n == 0) { vv0 = 1.f; vv1 = vv2 = vv3 = 0.f; }

        const float vv[4] = {vv0, vv1, vv2, vv3};
        const float aa[4] = {aa0, aa1, aa2, aa3};
        const float* Bn = Bw + (size_t)n * 64;      // wave-uniform -> s_load
        float H00 = 0.f, H01 = 0.f, H10 = 0.f, H11 = 0.f;
        #pragma unroll
        for (int i = 0; i < 4; ++i) {
            #pragma unroll
            for (int l = 0; l < 4; ++l) {
                const float c = vv[i] * aa[l];
                const int   q = (i * 4 + l) * 4;
                H00 = fmaf(c, Bn[q + 0], H00);
                H01 = fmaf(c, Bn[q + 1], H01);
                H10 = fmaf(c, Bn[q + 2], H10);
                H11 = fmaf(c, Bn[q + 3], H11);
            }
        }
        const float rh = sc * RSQ(H00*H00 + H01*H01 + H10*H10 + H11*H11);
        H00 *= rh; H01 *= rh; H10 *= rh; H11 *= rh;
        if (__builtin_isnan(H00)) H00 = 0.f;
        if (__builtin_isnan(H01)) H01 = 0.f;
        if (__builtin_isnan(H10)) H10 = 0.f;
        if (__builtin_isnan(H11)) H11 = 0.f;
        H00 = fmaxf(H00, 0.f); H01 = fmaxf(H01, 0.f);
        H10 = fmaxf(H10, 0.f); H11 = fmaxf(H11, 0.f);

        yr[2*kk]     = fmaf(H01, xc[kk], H00 * xa[kk]);
        yr[2*kk + 1] = fmaf(H11, xc[kk], H10 * xa[kk]);

        if (kk > 0) {   // u <- M[kk].u  (raw suffix for site n-1)
            const float t0 = M[kk][0]*u0  + M[kk][1]*u1  + M[kk][2]*u2  + M[kk][3]*u3;
            const float t1 = M[kk][4]*u0  + M[kk][5]*u1  + M[kk][6]*u2  + M[kk][7]*u3;
            const float t2 = M[kk][8]*u0  + M[kk][9]*u1  + M[kk][10]*u2 + M[kk][11]*u3;
            const float t3 = M[kk][12]*u0 + M[kk][13]*u1 + M[kk][14]*u2 + M[kk][15]*u3;
            u0 = t0; u1 = t1; u2 = t2; u3 = t3;
        }
    }

    // ---- direct y stores: 32B/thread contiguous --------------------------
    {
        float* yp = y + (size_t)blockIdx.x * 8192 + bb * 128 + n0 * 2;
        *(float4*)yp       = make_float4(yr[0], yr[1], yr[2], yr[3]);
        *(float4*)(yp + 4) = make_float4(yr[4], yr[5], yr[6], yr[7]);
    }
}

extern "C" void kernel_launch(void* const* d_in, const int* in_sizes, int n_in,
                              void* d_out, int out_size, void* d_ws, size_t ws_size,
                              hipStream_t stream) {
    const float* x     = (const float*)d_in[0];
    const float* A     = (const float*)d_in[1];
    const float* B     = (const float*)d_in[2];
    const float* scale = (const float*)d_in[3];
    float* yp = (float*)d_out;
    const int batch  = in_sizes[0] / 128;    // 16384
    const int blocks = batch / 64;           // 256 blocks x 1024 threads
    tdvp_kernel<<<blocks, 1024, 0, stream>>>(x, A, B, scale, yp);
}

// Round 10
// 73.777 us; speedup vs baseline: 1.0768x; 1.0360x over previous
//
#include <hip/hip_runtime.h>
#include <math.h>

// TDVP_V2: BATCH=16384 chains, N=64 sites, D=4, DIN=DOUT=2.
// v24: packed-f32 math (v_pk_fma_f32) + drop redundant epilogue norms.
// LEDGER (JSON): v15/17/18 = 77.70 | v20 = 75.75 | v21b NT = 75.91 (flat)
// | v22 2blk/CU+LDS A/B = 79.44 (regress) | v23 direct-x/y 1-barrier = 76.43
// (~neutral; fill was +1us that run). Calibration (v19): floor ~49 (42 fill
// + 7 small nodes), kernel ~26.5 = F ~16.5 (cold-mem ~5 + launch/drain +
// serial chains) + steady ~10 (VALU issue 4.7, LDS 5.1, rest dep-stalls).
// Structural levers exhausted; v24 cuts the ISSUE COUNT:
//  1. ext_vector float2 + __builtin_elementwise_fma -> v_pk_fma_f32 in
//     prefix scan (16->8 ops/iter), P-build (64->32/step), fwd walk,
//     epilogue H (64->32/site), Frobenius sums. Suffix scan + bwd update
//     need non-adjacent column pairs -> stay scalar. ~ -25% VALU/thread.
//  2. Drop vv/aa normalizations in epilogue: H is renormalized by rh, so
//     scale cancels exactly; removes 8 rsq + two 4-dots from the serial
//     backward chain. n==0/63 overrides + NaN->0 + relu unchanged.
// Base = v23 (direct x/y, single barrier, SGPR A/B, M cache, norm-free
// interleaved scans, b128 row-quads).
// Predicted: kernel -1.5..-2.5 => JSON ~73.5-75.0; absmax <= ~0.004.
// Pre-commit: if flat (>=75.3) => latency/dependency floor, ROOFLINE call.

#define RSQ(x) __builtin_amdgcn_rsqf((x) + 1e-30f)

typedef float f2 __attribute__((ext_vector_type(2)));
#define PKFMA(a, b, c) __builtin_elementwise_fma((f2)(a), (f2)(b), (f2)(c))

__global__ __launch_bounds__(1024, 4)
void tdvp_kernel(const float* __restrict__ x,
                 const float* __restrict__ A,
                 const float* __restrict__ Bw,
                 const float* __restrict__ scale,
                 float* __restrict__ y)
{
    // sP: [16 t][4 q][64 bb][4] = 64 KB
    __shared__ float sP[16384];

    const int tid = threadIdx.x;
    const int bb  = tid & 63;                                  // chain in block
    const int s   = __builtin_amdgcn_readfirstlane(tid >> 6);  // segment 0..15

    // ---- direct x loads: 32B/thread contiguous (sites n0..n0+3) ----------
    const int n0 = s * 4;
    const float* xp = x + (size_t)blockIdx.x * 8192 + bb * 128 + n0 * 2;
    const float4 xv0 = *(const float4*)xp;
    const float4 xv1 = *(const float4*)(xp + 4);
    float xa[4], xc[4];
    {
        float r;
        r = RSQ(xv0.x*xv0.x + xv0.y*xv0.y); xa[0]=xv0.x*r; xc[0]=xv0.y*r;
        r = RSQ(xv0.z*xv0.z + xv0.w*xv0.w); xa[1]=xv0.z*r; xc[1]=xv0.w*r;
        r = RSQ(xv1.x*xv1.x + xv1.y*xv1.y); xa[2]=xv1.x*r; xc[2]=xv1.y*r;
        r = RSQ(xv1.z*xv1.z + xv1.w*xv1.w); xa[3]=xv1.z*r; xc[3]=xv1.w*r;
    }

    // ---- M cache as column-pair float2s: M01[k][r]=(M[r][0],M[r][1]) -----
    f2 M01[4][4], M23[4][4];
    #pragma unroll
    for (int k = 0; k < 4; ++k) {
        const float* Ak = A + (size_t)(n0 + k) * 32;   // wave-uniform -> s_load
        #pragma unroll
        for (int r = 0; r < 4; ++r) {
            M01[k][r].x = fmaf(xc[k], Ak[8*r + 1], xa[k] * Ak[8*r + 0]);
            M01[k][r].y = fmaf(xc[k], Ak[8*r + 3], xa[k] * Ak[8*r + 2]);
            M23[k][r].x = fmaf(xc[k], Ak[8*r + 5], xa[k] * Ak[8*r + 4]);
            M23[k][r].y = fmaf(xc[k], Ak[8*r + 7], xa[k] * Ak[8*r + 6]);
        }
    }

    // ---- phase 1: P = M0*M1*M2*M3, Frobenius-normalized -> sP (pk) -------
    {
        f2 P01[4], P23[4];
        #pragma unroll
        for (int r = 0; r < 4; ++r) { P01[r] = M01[0][r]; P23[r] = M23[0][r]; }
        #pragma unroll
        for (int k = 1; k < 4; ++k) {
            f2 Q01[4], Q23[4];
            #pragma unroll
            for (int i = 0; i < 4; ++i) {
                Q01[i] = PKFMA(P01[i].x, M01[k][0],
                         PKFMA(P01[i].y, M01[k][1],
                         PKFMA(P23[i].x, M01[k][2], (f2)(P23[i].y) * M01[k][3])));
                Q23[i] = PKFMA(P01[i].x, M23[k][0],
                         PKFMA(P01[i].y, M23[k][1],
                         PKFMA(P23[i].x, M23[k][2], (f2)(P23[i].y) * M23[k][3])));
            }
            #pragma unroll
            for (int i = 0; i < 4; ++i) { P01[i] = Q01[i]; P23[i] = Q23[i]; }
        }
        f2 ssv = P01[0] * P01[0];
        ssv = PKFMA(P01[1], P01[1], ssv);
        ssv = PKFMA(P01[2], P01[2], ssv);
        ssv = PKFMA(P01[3], P01[3], ssv);
        ssv = PKFMA(P23[0], P23[0], ssv);
        ssv = PKFMA(P23[1], P23[1], ssv);
        ssv = PKFMA(P23[2], P23[2], ssv);
        ssv = PKFMA(P23[3], P23[3], ssv);
        const float rn = RSQ(ssv.x + ssv.y);
        #pragma unroll
        for (int q = 0; q < 4; ++q)
            *(float4*)&sP[s * 1024 + q * 256 + bb * 4] =
                make_float4(P01[q].x*rn, P01[q].y*rn, P23[q].x*rn, P23[q].y*rn);
    }
    __syncthreads();   // the ONLY barrier

    // ---- phase 2: interleaved scans (prefix pk, suffix scalar) -----------
    f2 vA = {1.f, 0.f}, vB = {0.f, 0.f};     // prefix (v0,v1),(v2,v3)
    float u0 = 1.f, u1 = 0.f, u2 = 0.f, u3 = 0.f;
    const int nsuf = 15 - s;
    #pragma unroll
    for (int i = 0; i < 15; ++i) {
        if (i < s) {               // wave-uniform
            const float4* pp = (const float4*)&sP[i * 1024 + bb * 4];
            const float4 r0 = pp[0], r1 = pp[64], r2 = pp[128], r3 = pp[192];
            const f2 r0l = {r0.x, r0.y}, r0h = {r0.z, r0.w};
            const f2 r1l = {r1.x, r1.y}, r1h = {r1.z, r1.w};
            const f2 r2l = {r2.x, r2.y}, r2h = {r2.z, r2.w};
            const f2 r3l = {r3.x, r3.y}, r3h = {r3.z, r3.w};
            const f2 w01 = PKFMA(vA.x, r0l, PKFMA(vA.y, r1l,
                           PKFMA(vB.x, r2l, (f2)(vB.y) * r3l)));
            const f2 w23 = PKFMA(vA.x, r0h, PKFMA(vA.y, r1h,
                           PKFMA(vB.x, r2h, (f2)(vB.y) * r3h)));
            vA = w01; vB = w23;
        }
        if (i < nsuf) {            // wave-uniform, t = 15 - i
            const float4* pp = (const float4*)&sP[(15 - i) * 1024 + bb * 4];
            const float4 r0 = pp[0], r1 = pp[64], r2 = pp[128], r3 = pp[192];
            const float w0 = r0.x*u0 + r0.y*u1 + r0.z*u2 + r0.w*u3;
            const float w1 = r1.x*u0 + r1.y*u1 + r1.z*u2 + r1.w*u3;
            const float w2 = r2.x*u0 + r2.y*u1 + r2.z*u2 + r2.w*u3;
            const float w3 = r3.x*u0 + r3.y*u1 + r3.z*u2 + r3.w*u3;
            u0 = w0; u1 = w1; u2 = w2; u3 = w3;
        }
    }

    // ---- phase 3a: forward walk, vl per site (pk, cached M) --------------
    f2 vl01[4], vl23[4];
    {
        f2 aA = vA, aB = vB;
        #pragma unroll
        for (int k = 0; k < 4; ++k) {
            vl01[k] = aA; vl23[k] = aB;
            if (k == 3) break;
            const f2 t01 = PKFMA(aA.x, M01[k][0], PKFMA(aA.y, M01[k][1],
                           PKFMA(aB.x, M01[k][2], (f2)(aB.y) * M01[k][3])));
            const f2 t23 = PKFMA(aA.x, M23[k][0], PKFMA(aA.y, M23[k][1],
                           PKFMA(aB.x, M23[k][2], (f2)(aB.y) * M23[k][3])));
            aA = t01; aB = t23;
        }
    }

    // ---- phase 3b: backward walk + fused epilogue (pk H, no vv/aa norm) --
    const float sc = scale[0];
    float yr[8];
    #pragma unroll
    for (int kk = 3; kk >= 0; --kk) {
        const int n = n0 + kk;

        // aa = raw suffix (scale cancels in rh); n==63 override
        float aa0 = u0, aa1 = u1, aa2 = u2, aa3 = u3;
        if (n == 63) { aa0 = 1.f; aa1 = aa2 = aa3 = 0.f; }

        // vv = raw vl (scale cancels in rh); n==0 override
        f2 vv01 = vl01[kk], vv23 = vl23[kk];
        if (n == 0) { vv01.x = 1.f; vv01.y = 0.f; vv23.x = 0.f; vv23.y = 0.f; }

        const float vv[4] = {vv01.x, vv01.y, vv23.x, vv23.y};
        const float aa[4] = {aa0, aa1, aa2, aa3};
        const float* Bn = Bw + (size_t)n * 64;      // wave-uniform -> s_load
        f2 H0 = {0.f, 0.f}, H1 = {0.f, 0.f};        // (H00,H01), (H10,H11)
        #pragma unroll
        for (int i = 0; i < 4; ++i) {
            #pragma unroll
            for (int l = 0; l < 4; ++l) {
                const float c = vv[i] * aa[l];
                const int   q = (i * 4 + l) * 4;
                const f2 b01 = {Bn[q + 0], Bn[q + 1]};
                const f2 b23 = {Bn[q + 2], Bn[q + 3]};
                H0 = PKFMA(c, b01, H0);
                H1 = PKFMA(c, b23, H1);
            }
        }
        const float rh = sc * RSQ(H0.x*H0.x + H0.y*H0.y + H1.x*H1.x + H1.y*H1.y);
        float H00 = H0.x * rh, H01 = H0.y * rh, H10 = H1.x * rh, H11 = H1.y * rh;
        if (__builtin_isnan(H00)) H00 = 0.f;
        if (__builtin_isnan(H01)) H01 = 0.f;
        if (__builtin_isnan(H10)) H10 = 0.f;
        if (__builtin_isnan(H11)) H11 = 0.f;
        H00 = fmaxf(H00, 0.f); H01 = fmaxf(H01, 0.f);
        H10 = fmaxf(H10, 0.f); H11 = fmaxf(H11, 0.f);

        yr[2*kk]     = fmaf(H01, xc[kk], H00 * xa[kk]);
        yr[2*kk + 1] = fmaf(H11, xc[kk], H10 * xa[kk]);

        if (kk > 0) {   // u <- M[kk].u  (raw suffix for site n-1; scalar)
            const float t0 = M01[kk][0].x*u0 + M01[kk][0].y*u1 + M23[kk][0].x*u2 + M23[kk][0].y*u3;
            const float t1 = M01[kk][1].x*u0 + M01[kk][1].y*u1 + M23[kk][1].x*u2 + M23[kk][1].y*u3;
            const float t2 = M01[kk][2].x*u0 + M01[kk][2].y*u1 + M23[kk][2].x*u2 + M23[kk][2].y*u3;
            const float t3 = M01[kk][3].x*u0 + M01[kk][3].y*u1 + M23[kk][3].x*u2 + M23[kk][3].y*u3;
            u0 = t0; u1 = t1; u2 = t2; u3 = t3;
        }
    }

    // ---- direct y stores: 32B/thread contiguous --------------------------
    {
        float* yp = y + (size_t)blockIdx.x * 8192 + bb * 128 + n0 * 2;
        *(float4*)yp       = make_float4(yr[0], yr[1], yr[2], yr[3]);
        *(float4*)(yp + 4) = make_float4(yr[4], yr[5], yr[6], yr[7]);
    }
}

extern "C" void kernel_launch(void* const* d_in, const int* in_sizes, int n_in,
                              void* d_out, int out_size, void* d_ws, size_t ws_size,
                              hipStream_t stream) {
    const float* x     = (const float*)d_in[0];
    const float* A     = (const float*)d_in[1];
    const float* B     = (const float*)d_in[2];
    const float* scale = (const float*)d_in[3];
    float* yp = (float*)d_out;
    const int batch  = in_sizes[0] / 128;    // 16384
    const int blocks = batch / 64;           // 256 blocks x 1024 threads
    tdvp_kernel<<<blocks, 1024, 0, stream>>>(x, A, B, scale, yp);
}

// Round 12
// 72.812 us; speedup vs baseline: 1.0910x; 1.0133x over previous
//
#include <hip/hip_runtime.h>
#include <math.h>

// TDVP_V2: BATCH=16384 chains, N=64 sites, D=4, DIN=DOUT=2.
// v25b: v25 with compile fix — PKFMA as inline functions (macro version
// split braced-init-list commas into extra macro args). Semantics identical.
// LEDGER (JSON): v15/17/18 77.70 | v20 75.75 | v21b 75.91 (flat) | v22 79.44
// (regress) | v23 76.43 (~neutral, fill +1) | v24 pk_fma+norm-drop = 73.78
// (MATCHED prediction 73.5-75.0). Calibration: harness floor ~49.1 (42 fill
// + 7 nodes); kernel ~24.7 = F ~16.5 + steady ~8.
// v25 changes (v24 otherwise identical):
//  1. suffix scan matvec: w_i=dot(r_i,u) as r_lo*u01 + r_hi*u23 (pk) +
//     horizontal add: 12 instr vs 16, chain 3 vs 4.
//  2. backward u-update: same pairing, 12 vs 16, on the serial chain.
//  3. epilogue c[i][l]=vv_i*aa_l: 8 v_pk_mul vs 16 scalar; H = 8pk+32pk.
// Predicted: JSON -> ~72.7-73.5; absmax ~0.0039.
// PRE-COMMIT: flat/regress => latency floor vs 49us harness => ROOFLINE.

#define RSQ(x) __builtin_amdgcn_rsqf((x) + 1e-30f)

typedef float f2 __attribute__((ext_vector_type(2)));

static __device__ __forceinline__ f2 pkfma(f2 a, f2 b, f2 c) {
    return __builtin_elementwise_fma(a, b, c);
}
static __device__ __forceinline__ f2 pkfma(float a, f2 b, f2 c) {
    return __builtin_elementwise_fma((f2)(a), b, c);
}

__global__ __launch_bounds__(1024, 4)
void tdvp_kernel(const float* __restrict__ x,
                 const float* __restrict__ A,
                 const float* __restrict__ Bw,
                 const float* __restrict__ scale,
                 float* __restrict__ y)
{
    // sP: [16 t][4 q][64 bb][4] = 64 KB
    __shared__ float sP[16384];

    const int tid = threadIdx.x;
    const int bb  = tid & 63;                                  // chain in block
    const int s   = __builtin_amdgcn_readfirstlane(tid >> 6);  // segment 0..15

    // ---- direct x loads: 32B/thread contiguous (sites n0..n0+3) ----------
    const int n0 = s * 4;
    const float* xp = x + (size_t)blockIdx.x * 8192 + bb * 128 + n0 * 2;
    const float4 xv0 = *(const float4*)xp;
    const float4 xv1 = *(const float4*)(xp + 4);
    float xa[4], xc[4];
    {
        float r;
        r = RSQ(xv0.x*xv0.x + xv0.y*xv0.y); xa[0]=xv0.x*r; xc[0]=xv0.y*r;
        r = RSQ(xv0.z*xv0.z + xv0.w*xv0.w); xa[1]=xv0.z*r; xc[1]=xv0.w*r;
        r = RSQ(xv1.x*xv1.x + xv1.y*xv1.y); xa[2]=xv1.x*r; xc[2]=xv1.y*r;
        r = RSQ(xv1.z*xv1.z + xv1.w*xv1.w); xa[3]=xv1.z*r; xc[3]=xv1.w*r;
    }

    // ---- M cache as column-pair float2s: M01[k][r]=(M[r][0],M[r][1]) -----
    f2 M01[4][4], M23[4][4];
    #pragma unroll
    for (int k = 0; k < 4; ++k) {
        const float* Ak = A + (size_t)(n0 + k) * 32;   // wave-uniform -> s_load
        #pragma unroll
        for (int r = 0; r < 4; ++r) {
            M01[k][r].x = fmaf(xc[k], Ak[8*r + 1], xa[k] * Ak[8*r + 0]);
            M01[k][r].y = fmaf(xc[k], Ak[8*r + 3], xa[k] * Ak[8*r + 2]);
            M23[k][r].x = fmaf(xc[k], Ak[8*r + 5], xa[k] * Ak[8*r + 4]);
            M23[k][r].y = fmaf(xc[k], Ak[8*r + 7], xa[k] * Ak[8*r + 6]);
        }
    }

    // ---- phase 1: P = M0*M1*M2*M3, Frobenius-normalized -> sP (pk) -------
    {
        f2 P01[4], P23[4];
        #pragma unroll
        for (int r = 0; r < 4; ++r) { P01[r] = M01[0][r]; P23[r] = M23[0][r]; }
        #pragma unroll
        for (int k = 1; k < 4; ++k) {
            f2 Q01[4], Q23[4];
            #pragma unroll
            for (int i = 0; i < 4; ++i) {
                Q01[i] = pkfma(P01[i].x, M01[k][0],
                         pkfma(P01[i].y, M01[k][1],
                         pkfma(P23[i].x, M01[k][2], (f2)(P23[i].y) * M01[k][3])));
                Q23[i] = pkfma(P01[i].x, M23[k][0],
                         pkfma(P01[i].y, M23[k][1],
                         pkfma(P23[i].x, M23[k][2], (f2)(P23[i].y) * M23[k][3])));
            }
            #pragma unroll
            for (int i = 0; i < 4; ++i) { P01[i] = Q01[i]; P23[i] = Q23[i]; }
        }
        f2 ssv = P01[0] * P01[0];
        ssv = pkfma(P01[1], P01[1], ssv);
        ssv = pkfma(P01[2], P01[2], ssv);
        ssv = pkfma(P01[3], P01[3], ssv);
        ssv = pkfma(P23[0], P23[0], ssv);
        ssv = pkfma(P23[1], P23[1], ssv);
        ssv = pkfma(P23[2], P23[2], ssv);
        ssv = pkfma(P23[3], P23[3], ssv);
        const float rn = RSQ(ssv.x + ssv.y);
        #pragma unroll
        for (int q = 0; q < 4; ++q)
            *(float4*)&sP[s * 1024 + q * 256 + bb * 4] =
                make_float4(P01[q].x*rn, P01[q].y*rn, P23[q].x*rn, P23[q].y*rn);
    }
    __syncthreads();   // the ONLY barrier

    // ---- phase 2: interleaved scans (prefix pk, suffix pair-dot pk) ------
    f2 vA = {1.f, 0.f}, vB = {0.f, 0.f};     // prefix (v0,v1),(v2,v3)
    f2 u01 = {1.f, 0.f}, u23 = {0.f, 0.f};   // suffix (u0,u1),(u2,u3)
    const int nsuf = 15 - s;
    #pragma unroll
    for (int i = 0; i < 15; ++i) {
        if (i < s) {               // wave-uniform
            const float4* pp = (const float4*)&sP[i * 1024 + bb * 4];
            const float4 r0 = pp[0], r1 = pp[64], r2 = pp[128], r3 = pp[192];
            const f2 r0l = {r0.x, r0.y}, r0h = {r0.z, r0.w};
            const f2 r1l = {r1.x, r1.y}, r1h = {r1.z, r1.w};
            const f2 r2l = {r2.x, r2.y}, r2h = {r2.z, r2.w};
            const f2 r3l = {r3.x, r3.y}, r3h = {r3.z, r3.w};
            const f2 w01 = pkfma(vA.x, r0l, pkfma(vA.y, r1l,
                           pkfma(vB.x, r2l, (f2)(vB.y) * r3l)));
            const f2 w23 = pkfma(vA.x, r0h, pkfma(vA.y, r1h,
                           pkfma(vB.x, r2h, (f2)(vB.y) * r3h)));
            vA = w01; vB = w23;
        }
        if (i < nsuf) {            // wave-uniform, t = 15 - i
            const float4* pp = (const float4*)&sP[(15 - i) * 1024 + bb * 4];
            const float4 r0 = pp[0], r1 = pp[64], r2 = pp[128], r3 = pp[192];
            const f2 r0l = {r0.x, r0.y}, r0h = {r0.z, r0.w};
            const f2 r1l = {r1.x, r1.y}, r1h = {r1.z, r1.w};
            const f2 r2l = {r2.x, r2.y}, r2h = {r2.z, r2.w};
            const f2 r3l = {r3.x, r3.y}, r3h = {r3.z, r3.w};
            const f2 t0 = pkfma(r0h, u23, r0l * u01);
            const f2 t1 = pkfma(r1h, u23, r1l * u01);
            const f2 t2 = pkfma(r2h, u23, r2l * u01);
            const f2 t3 = pkfma(r3h, u23, r3l * u01);
            u01.x = t0.x + t0.y; u01.y = t1.x + t1.y;
            u23.x = t2.x + t2.y; u23.y = t3.x + t3.y;
        }
    }

    // ---- phase 3a: forward walk, vl per site (pk, cached M) --------------
    f2 vl01[4], vl23[4];
    {
        f2 aA = vA, aB = vB;
        #pragma unroll
        for (int k = 0; k < 4; ++k) {
            vl01[k] = aA; vl23[k] = aB;
            if (k == 3) break;
            const f2 t01 = pkfma(aA.x, M01[k][0], pkfma(aA.y, M01[k][1],
                           pkfma(aB.x, M01[k][2], (f2)(aB.y) * M01[k][3])));
            const f2 t23 = pkfma(aA.x, M23[k][0], pkfma(aA.y, M23[k][1],
                           pkfma(aB.x, M23[k][2], (f2)(aB.y) * M23[k][3])));
            aA = t01; aB = t23;
        }
    }

    // ---- phase 3b: backward walk + fused epilogue (all-pk) ---------------
    const float sc = scale[0];
    float yr[8];
    #pragma unroll
    for (int kk = 3; kk >= 0; --kk) {
        const int n = n0 + kk;

        // aa = raw suffix (scale cancels in rh); n==63 override
        f2 aa01 = u01, aa23 = u23;
        if (n == 63) { aa01.x = 1.f; aa01.y = 0.f; aa23.x = 0.f; aa23.y = 0.f; }

        // vv = raw vl (scale cancels in rh); n==0 override
        f2 vv01 = vl01[kk], vv23 = vl23[kk];
        if (n == 0) { vv01.x = 1.f; vv01.y = 0.f; vv23.x = 0.f; vv23.y = 0.f; }

        const float vv[4] = {vv01.x, vv01.y, vv23.x, vv23.y};
        const float* Bn = Bw + (size_t)n * 64;      // wave-uniform -> s_load
        f2 H0 = {0.f, 0.f}, H1 = {0.f, 0.f};        // (H00,H01), (H10,H11)
        #pragma unroll
        for (int i = 0; i < 4; ++i) {
            const f2 cl = (f2)(vv[i]) * aa01;       // (c_i0, c_i1)
            const f2 ch = (f2)(vv[i]) * aa23;       // (c_i2, c_i3)
            const int q = i * 16;
            f2 b;
            b.x = Bn[q+ 0]; b.y = Bn[q+ 1]; H0 = pkfma(cl.x, b, H0);
            b.x = Bn[q+ 2]; b.y = Bn[q+ 3]; H1 = pkfma(cl.x, b, H1);
            b.x = Bn[q+ 4]; b.y = Bn[q+ 5]; H0 = pkfma(cl.y, b, H0);
            b.x = Bn[q+ 6]; b.y = Bn[q+ 7]; H1 = pkfma(cl.y, b, H1);
            b.x = Bn[q+ 8]; b.y = Bn[q+ 9]; H0 = pkfma(ch.x, b, H0);
            b.x = Bn[q+10]; b.y = Bn[q+11]; H1 = pkfma(ch.x, b, H1);
            b.x = Bn[q+12]; b.y = Bn[q+13]; H0 = pkfma(ch.y, b, H0);
            b.x = Bn[q+14]; b.y = Bn[q+15]; H1 = pkfma(ch.y, b, H1);
        }
        const float rh = sc * RSQ(H0.x*H0.x + H0.y*H0.y + H1.x*H1.x + H1.y*H1.y);
        float H00 = H0.x * rh, H01 = H0.y * rh, H10 = H1.x * rh, H11 = H1.y * rh;
        if (__builtin_isnan(H00)) H00 = 0.f;
        if (__builtin_isnan(H01)) H01 = 0.f;
        if (__builtin_isnan(H10)) H10 = 0.f;
        if (__builtin_isnan(H11)) H11 = 0.f;
        H00 = fmaxf(H00, 0.f); H01 = fmaxf(H01, 0.f);
        H10 = fmaxf(H10, 0.f); H11 = fmaxf(H11, 0.f);

        yr[2*kk]     = fmaf(H01, xc[kk], H00 * xa[kk]);
        yr[2*kk + 1] = fmaf(H11, xc[kk], H10 * xa[kk]);

        if (kk > 0) {   // u <- M[kk].u  (pair-dot pk, raw suffix) ----------
            const f2 t0 = pkfma(M23[kk][0], u23, M01[kk][0] * u01);
            const f2 t1 = pkfma(M23[kk][1], u23, M01[kk][1] * u01);
            const f2 t2 = pkfma(M23[kk][2], u23, M01[kk][2] * u01);
            const f2 t3 = pkfma(M23[kk][3], u23, M01[kk][3] * u01);
            u01.x = t0.x + t0.y; u01.y = t1.x + t1.y;
            u23.x = t2.x + t2.y; u23.y = t3.x + t3.y;
        }
    }

    // ---- direct y stores: 32B/thread contiguous --------------------------
    {
        float* yp = y + (size_t)blockIdx.x * 8192 + bb * 128 + n0 * 2;
        *(float4*)yp       = make_float4(yr[0], yr[1], yr[2], yr[3]);
        *(float4*)(yp + 4) = make_float4(yr[4], yr[5], yr[6], yr[7]);
    }
}

extern "C" void kernel_launch(void* const* d_in, const int* in_sizes, int n_in,
                              void* d_out, int out_size, void* d_ws, size_t ws_size,
                              hipStream_t stream) {
    const float* x     = (const float*)d_in[0];
    const float* A     = (const float*)d_in[1];
    const float* B     = (const float*)d_in[2];
    const float* scale = (const float*)d_in[3];
    float* yp = (float*)d_out;
    const int batch  = in_sizes[0] / 128;    // 16384
    const int blocks = batch / 64;           // 256 blocks x 1024 threads
    tdvp_kernel<<<blocks, 1024, 0, stream>>>(x, A, B, scale, yp);
}